// Round 6
// baseline (905.267 us; speedup 1.0000x reference)
//
#include <hip/hip_runtime.h>
#include <math.h>

#define EMB 128
#define NH 8
#define DH 16
#define HID 256
#define NODE 1000
#define PATCH 196
#define NKEY (NODE + PATCH)   // 1196
#define BB 8
#define POMO 1000
#define KT 16                  // attention key tile
#define SCH 6                  // key-split chunks
#define CKEYS 200              // keys per chunk (last = 196)
#define TILES16 16             // ceil(1000/64) row tiles
#define TROWS 64               // rows per tile
#define ROWS 4                 // rows per thread

// partial buffers alias d_out (8M floats):
// pacc: [b][tile16][chunk][row64][h][16] = 8*16*6*64*8*16 = 6,291,456 floats
// pl  : [b][tile16][chunk][h][row64]     = 8*16*6*8*64    =   393,216 floats
#define PACC_FLOATS 6291456L

__device__ __forceinline__ float tanh10(float x) {
    float e = __expf(2.0f * x);
    return 10.0f * (1.0f - 2.0f / (e + 1.0f));
}

// ---------------- hypernet stage 1: pref -> mid[15] -------------------------
__global__ __launch_bounds__(256) void hyper_mid_kernel(
    const float* __restrict__ pref,
    const float* __restrict__ fc1_w, const float* __restrict__ fc1_b,
    const float* __restrict__ fc2_w, const float* __restrict__ fc2_b,
    const float* __restrict__ fc3_w, const float* __restrict__ fc3_b,
    float* __restrict__ gmid)
{
    __shared__ float h1[HID];
    __shared__ float h2[HID];
    int t = threadIdx.x;
    float p0 = pref[0], p1 = pref[1], p2 = pref[2];
    h1[t] = fc1_b[t] + p0 * fc1_w[t * 3 + 0] + p1 * fc1_w[t * 3 + 1] + p2 * fc1_w[t * 3 + 2];
    __syncthreads();
    {
        float s = fc2_b[t];
        const float4* w4 = (const float4*)(fc2_w + t * HID);
        const float4* h4 = (const float4*)h1;
        for (int j = 0; j < HID / 4; ++j) {
            float4 w = w4[j], x = h4[j];
            s += x.x * w.x + x.y * w.y + x.z * w.z + x.w * w.w;
        }
        h2[t] = s;
    }
    __syncthreads();
    if (t < 15) {
        float s = fc3_b[t];
        const float4* w4 = (const float4*)(fc3_w + t * HID);
        const float4* h4 = (const float4*)h2;
        for (int j = 0; j < HID / 4; ++j) {
            float4 w = w4[j], x = h4[j];
            s += x.x * w.x + x.y * w.y + x.z * w.z + x.w * w.w;
        }
        gmid[t] = s;
    }
}

// ---------------- hypernet stage 2: mid -> 5 weight matrices ----------------
__global__ __launch_bounds__(256) void hyper_expand_kernel(
    const float* __restrict__ gmid,
    const float* __restrict__ wqf, const float* __restrict__ wql,
    const float* __restrict__ wk,  const float* __restrict__ wv,
    const float* __restrict__ wc,  float* __restrict__ W5)
{
    int id = blockIdx.x;                 // 40 blocks: 5 mats x 8 segments
    int mat = id >> 3;
    int x0 = (id & 7) * 2048 + threadIdx.x * 8;
    const float* w = (mat == 0) ? wqf : (mat == 1) ? wql : (mat == 2) ? wk : (mat == 3) ? wv : wc;
    float m0 = gmid[mat * 3 + 0], m1 = gmid[mat * 3 + 1], m2 = gmid[mat * 3 + 2];
    float* dst = W5 + mat * EMB * EMB;
    #pragma unroll
    for (int i = 0; i < 8; ++i) {
        int x = x0 + i;
        dst[x] = m0 * w[x * 3 + 0] + m1 * w[x * 3 + 1] + m2 * w[x * 3 + 2];
    }
}

// ---------------- K,V projection of encoded_nodes ---------------------------
__global__ __launch_bounds__(256) void kv_proj_kernel(
    const float* __restrict__ nodes, const float* __restrict__ W5,
    float* __restrict__ Kb, float* __restrict__ Vb)
{
    __shared__ float xs[32][EMB];
    int t = threadIdx.x;
    long r0 = (long)blockIdx.x * 32;            // over BB*NKEY = 9568 (299*32 exact)
    const float4* s4 = (const float4*)(nodes + r0 * EMB);
    float4* x4p = (float4*)&xs[0][0];
    for (int i = t; i < 32 * EMB / 4; i += 256) x4p[i] = s4[i];
    __syncthreads();
    int o = t;
    const float* W = (o < EMB) ? (W5 + 2 * EMB * EMB + o * EMB)
                               : (W5 + 3 * EMB * EMB + (o - EMB) * EMB);
    float acc[32];
    #pragma unroll
    for (int r = 0; r < 32; ++r) acc[r] = 0.f;
    for (int e = 0; e < EMB; e += 4) {
        float4 w4 = *(const float4*)&W[e];
        #pragma unroll
        for (int r = 0; r < 32; ++r) {
            float4 x4 = *(const float4*)&xs[r][e];
            acc[r] += x4.x * w4.x + x4.y * w4.y + x4.z * w4.z + x4.w * w4.w;
        }
    }
    float* dst = (o < EMB) ? (Kb + r0 * EMB + o) : (Vb + r0 * EMB + (o - EMB));
    #pragma unroll
    for (int r = 0; r < 32; ++r) dst[(long)r * EMB] = acc[r];
}

// ---------------- Q projection: q1@Wqf.T + last@Wql.T -----------------------
__global__ __launch_bounds__(256) void q_proj_kernel(
    const float* __restrict__ q1, const float* __restrict__ lastn,
    const float* __restrict__ W5, float* __restrict__ Qb)
{
    __shared__ float xa[32][EMB];
    __shared__ float xb[32][EMB];
    int t = threadIdx.x;
    long r0 = (long)blockIdx.x * 32;            // over 8000 (250*32 exact)
    const float4* a4 = (const float4*)(q1 + r0 * EMB);
    const float4* b4 = (const float4*)(lastn + r0 * EMB);
    float4* xap = (float4*)&xa[0][0];
    float4* xbp = (float4*)&xb[0][0];
    for (int i = t; i < 32 * EMB / 4; i += 256) { xap[i] = a4[i]; xbp[i] = b4[i]; }
    __syncthreads();
    int o = t & 127;
    int rbase = (t >> 7) * 16;
    const float* Wf = W5 + 0 * EMB * EMB + o * EMB;
    const float* Wl = W5 + 1 * EMB * EMB + o * EMB;
    float acc[16];
    #pragma unroll
    for (int r = 0; r < 16; ++r) acc[r] = 0.f;
    for (int e = 0; e < EMB; e += 4) {
        float4 wf = *(const float4*)&Wf[e];
        float4 wl = *(const float4*)&Wl[e];
        #pragma unroll
        for (int r = 0; r < 16; ++r) {
            float4 va = *(const float4*)&xa[rbase + r][e];
            float4 vb = *(const float4*)&xb[rbase + r][e];
            acc[r] += va.x * wf.x + va.y * wf.y + va.z * wf.z + va.w * wf.w
                    + vb.x * wl.x + vb.y * wl.y + vb.z * wl.z + vb.w * wl.w;
        }
    }
    #pragma unroll
    for (int r = 0; r < 16; ++r) Qb[(r0 + rbase + r) * EMB + o] = acc[r];
}

// ---------------- fused masked MHA, key-split, no-max-shift, R=4 ------------
// grid (8, 16, 6): x=b (XCD-aligned: per-b mask/KV stays in one XCD L2),
// y=64-row tile, z=key chunk. block 128: h=t>>4, rr=t&15; thread owns rows
// {4rr..4rr+3}. One K/V LDS read serves 4 rows -> LDS issue floor halves.
// Issue-early/write-late staging: global loads for tile t+1 issued right
// after LDS write of tile t; latency hides under 2048 FMAs of compute.
__global__ __launch_bounds__(128, 2) void attn_split_kernel(
    const float* __restrict__ Kb, const float* __restrict__ Vb,
    const float* __restrict__ Qb, const float* __restrict__ mask,
    float* __restrict__ pacc, float* __restrict__ pl)
{
    __shared__ float ks[KT][EMB];
    __shared__ float vs[KT][EMB];
    int t = threadIdx.x;
    int b = blockIdx.x;
    int tile = blockIdx.y;
    int c = blockIdx.z;
    int rr = t & 15;
    int h = t >> 4;
    int row0 = tile * TROWS + rr * ROWS;
    bool active = (row0 < POMO);
    int qrow = active ? row0 : (POMO - ROWS);   // clamped; results discarded
    int kstart = c * CKEYS;
    int kend = kstart + CKEYS; if (kend > NKEY) kend = NKEY;
    bool has_mask = (kstart < NODE);            // chunks 0..4 node keys, 5 patch

    float q[ROWS][DH], acc[ROWS][DH], l[ROWS];
    #pragma unroll
    for (int r = 0; r < ROWS; ++r) {
        const float4* qp = (const float4*)(Qb + ((long)b * POMO + qrow + r) * EMB + h * DH);
        #pragma unroll
        for (int i = 0; i < 4; ++i) {
            float4 v = qp[i];   // pre-scale by 1/sqrt(16): s = q.k + mask
            q[r][4*i+0] = v.x*0.25f; q[r][4*i+1] = v.y*0.25f;
            q[r][4*i+2] = v.z*0.25f; q[r][4*i+3] = v.w*0.25f;
        }
        #pragma unroll
        for (int i = 0; i < DH; ++i) acc[r][i] = 0.f;
        l[r] = 0.f;
    }

    const float4* ksrc = (const float4*)(Kb + (long)b * NKEY * EMB);
    const float4* vsrc = (const float4*)(Vb + (long)b * NKEY * EMB);
    const int max4 = NKEY * (EMB / 4) - 1;

    // prologue: issue loads for first tile
    float4 kr[4], vr[4];
    {
        int base4 = kstart * (EMB / 4);
        #pragma unroll
        for (int u = 0; u < 4; ++u) {
            int src = base4 + t + u * 128; if (src > max4) src = max4;
            kr[u] = ksrc[src]; vr[u] = vsrc[src];
        }
    }

    for (int t0 = kstart; t0 < kend; t0 += KT) {
        int valid = kend - t0; if (valid > KT) valid = KT;   // 16, 8 or 4
        __syncthreads();                       // prev compute done with LDS
        {   // write staged tile, then immediately issue next tile's loads
            float4* kd = (float4*)&ks[0][0];
            float4* vd = (float4*)&vs[0][0];
            #pragma unroll
            for (int u = 0; u < 4; ++u) {
                kd[t + u * 128] = kr[u];
                vd[t + u * 128] = vr[u];
            }
            int nt0 = t0 + KT;
            if (nt0 < kend) {
                int nb4 = nt0 * (EMB / 4);
                #pragma unroll
                for (int u = 0; u < 4; ++u) {
                    int src = nb4 + t + u * 128; if (src > max4) src = max4;
                    kr[u] = ksrc[src]; vr[u] = vsrc[src];
                }
            }
        }
        __syncthreads();

        int mv4 = valid >> 2;
        const float4 z4 = make_float4(0.f, 0.f, 0.f, 0.f);

#define TILE_COMPUTE(TAIL)                                                    \
        _Pragma("unroll")                                                     \
        for (int j4 = 0; j4 < KT / 4; ++j4) {                                 \
            float4 m4[ROWS];                                                  \
            if (has_mask) {                                                   \
                _Pragma("unroll")                                             \
                for (int r = 0; r < ROWS; ++r) {                              \
                    const float4* mp = (const float4*)(mask +                 \
                        ((long)b * POMO + qrow + r) * NODE + t0);             \
                    m4[r] = (!TAIL || j4 < mv4) ? mp[j4] : z4;                \
                }                                                             \
            } else {                                                          \
                _Pragma("unroll")                                             \
                for (int r = 0; r < ROWS; ++r) m4[r] = z4;                    \
            }                                                                 \
            _Pragma("unroll")                                                 \
            for (int jj = 0; jj < 4; ++jj) {                                  \
                int j = j4 * 4 + jj;                                          \
                float4 k0 = *(const float4*)&ks[j][h * DH + 0];               \
                float4 k1 = *(const float4*)&ks[j][h * DH + 4];               \
                float4 k2 = *(const float4*)&ks[j][h * DH + 8];               \
                float4 k3 = *(const float4*)&ks[j][h * DH + 12];              \
                float p[ROWS];                                                \
                _Pragma("unroll")                                             \
                for (int r = 0; r < ROWS; ++r) {                              \
                    float s = (jj == 0) ? m4[r].x : (jj == 1) ? m4[r].y       \
                            : (jj == 2) ? m4[r].z : m4[r].w;                  \
                    s += q[r][0]*k0.x + q[r][1]*k0.y + q[r][2]*k0.z + q[r][3]*k0.w; \
                    s += q[r][4]*k1.x + q[r][5]*k1.y + q[r][6]*k1.z + q[r][7]*k1.w; \
                    s += q[r][8]*k2.x + q[r][9]*k2.y + q[r][10]*k2.z + q[r][11]*k2.w; \
                    s += q[r][12]*k3.x + q[r][13]*k3.y + q[r][14]*k3.z + q[r][15]*k3.w; \
                    float pv = __expf(s);                                     \
                    if (TAIL && j >= valid) pv = 0.f;                         \
                    p[r] = pv; l[r] += pv;                                    \
                }                                                             \
                float4 v0 = *(const float4*)&vs[j][h * DH + 0];               \
                float4 v1 = *(const float4*)&vs[j][h * DH + 4];               \
                float4 v2 = *(const float4*)&vs[j][h * DH + 8];               \
                float4 v3 = *(const float4*)&vs[j][h * DH + 12];              \
                _Pragma("unroll")                                             \
                for (int r = 0; r < ROWS; ++r) {                              \
                    acc[r][0] += p[r]*v0.x;  acc[r][1] += p[r]*v0.y;          \
                    acc[r][2] += p[r]*v0.z;  acc[r][3] += p[r]*v0.w;          \
                    acc[r][4] += p[r]*v1.x;  acc[r][5] += p[r]*v1.y;          \
                    acc[r][6] += p[r]*v1.z;  acc[r][7] += p[r]*v1.w;          \
                    acc[r][8] += p[r]*v2.x;  acc[r][9] += p[r]*v2.y;          \
                    acc[r][10] += p[r]*v2.z; acc[r][11] += p[r]*v2.w;         \
                    acc[r][12] += p[r]*v3.x; acc[r][13] += p[r]*v3.y;         \
                    acc[r][14] += p[r]*v3.z; acc[r][15] += p[r]*v3.w;         \
                }                                                             \
            }                                                                 \
        }
        if (valid == KT) { TILE_COMPUTE(false) } else { TILE_COMPUTE(true) }
#undef TILE_COMPUTE
    }
    if (active) {
        long cb = ((long)(b * TILES16 + tile) * SCH + c);
        // pacc: [cb][row64][h][16] -- dense 64B records, full-line wave stores
        #pragma unroll
        for (int r = 0; r < ROWS; ++r) {
            long rec = ((cb * TROWS + rr * ROWS + r) * NH + h) * 16;
            #pragma unroll
            for (int i = 0; i < 4; ++i)
                *(float4*)&pacc[rec + 4*i] =
                    make_float4(acc[r][4*i], acc[r][4*i+1], acc[r][4*i+2], acc[r][4*i+3]);
        }
        // pl: [cb][h][row64] -- one float4 per thread, contiguous per (cb,h)
        *(float4*)&pl[(cb * NH + h) * TROWS + rr * ROWS] =
            make_float4(l[0], l[1], l[2], l[3]);
    }
}

// ---------------- merge key-split partials -> OC (plain sums) ---------------
__global__ __launch_bounds__(512) void attn_merge_kernel(
    const float* __restrict__ pacc, const float* __restrict__ pl,
    float* __restrict__ OC)
{
    int t = threadIdx.x;          // t = rt*8 + h
    int b = blockIdx.x, tile = blockIdx.y;
    int rt = t >> 3, h = t & 7;
    int row = tile * TROWS + rt;
    if (row >= POMO) return;
    long cb0 = (long)(b * TILES16 + tile) * SCH;
    const long cs_acc = (long)TROWS * NH * 16;   // 8192 floats per chunk
    long abase = cb0 * cs_acc + ((long)rt * NH + h) * 16;
    const long cs_pl = (long)NH * TROWS;         // 512 floats per chunk
    long lbase = cb0 * cs_pl + (long)h * TROWS + rt;

    float L = 0.f;
    float o[16];
    #pragma unroll
    for (int i = 0; i < 16; ++i) o[i] = 0.f;
    #pragma unroll
    for (int c = 0; c < SCH; ++c) {
        L += pl[lbase + c * cs_pl];
        #pragma unroll
        for (int i4 = 0; i4 < 4; ++i4) {
            float4 a = *(const float4*)&pacc[abase + c * cs_acc + 4 * i4];
            o[4*i4+0] += a.x; o[4*i4+1] += a.y;
            o[4*i4+2] += a.z; o[4*i4+3] += a.w;
        }
    }
    float inv = 1.0f / L;
    float* op = OC + ((long)b * POMO + row) * EMB + h * DH;
    #pragma unroll
    for (int i4 = 0; i4 < 4; ++i4)
        *(float4*)&op[4*i4] = make_float4(o[4*i4]*inv, o[4*i4+1]*inv,
                                          o[4*i4+2]*inv, o[4*i4+3]*inv);
}

// ---------------- multi-head combine: mh = oc @ Wc.T ------------------------
__global__ __launch_bounds__(256) void combine_kernel(
    const float* __restrict__ OC, const float* __restrict__ W5,
    float* __restrict__ MH)
{
    __shared__ float xs[32][EMB];
    int t = threadIdx.x;
    long r0 = (long)blockIdx.x * 32;            // over 8000
    const float4* s4 = (const float4*)(OC + r0 * EMB);
    float4* xp = (float4*)&xs[0][0];
    for (int i = t; i < 32 * EMB / 4; i += 256) xp[i] = s4[i];
    __syncthreads();
    int o = t & 127;
    int rbase = (t >> 7) * 16;
    const float* W = W5 + 4 * EMB * EMB + o * EMB;
    float acc[16];
    #pragma unroll
    for (int r = 0; r < 16; ++r) acc[r] = 0.f;
    for (int e = 0; e < EMB; e += 4) {
        float4 w4 = *(const float4*)&W[e];
        #pragma unroll
        for (int r = 0; r < 16; ++r) {
            float4 x4 = *(const float4*)&xs[rbase + r][e];
            acc[r] += x4.x * w4.x + x4.y * w4.y + x4.z * w4.z + x4.w * w4.w;
        }
    }
    #pragma unroll
    for (int r = 0; r < 16; ++r) MH[(r0 + rbase + r) * EMB + o] = acc[r];
}

// ---------------- logits: 10*tanh((mh @ nodes.T)/sqrt(128)) + mask ----------
__global__ __launch_bounds__(256) void logits_kernel(
    const float* __restrict__ MH, const float* __restrict__ nodes,
    const float* __restrict__ mask, float* __restrict__ out)
{
    __shared__ float As[64][65];   // [e][r]
    __shared__ float Bs[64][65];   // [e][c]
    int t = threadIdx.x;
    int b = blockIdx.x;
    int m0 = blockIdx.y * 64;
    int n0 = blockIdx.z * 64;
    int tc = t & 15, tr = t >> 4;
    float acc[4][4];
    #pragma unroll
    for (int i = 0; i < 4; ++i)
        #pragma unroll
        for (int j = 0; j < 4; ++j) acc[i][j] = 0.f;

    for (int e0 = 0; e0 < EMB; e0 += 64) {
        for (int i = t; i < 4096; i += 256) {
            int rr = i >> 6, e = i & 63;
            int n = n0 + rr;
            As[e][rr] = (n < POMO) ? MH[((long)b * POMO + n) * EMB + e0 + e] : 0.f;
        }
        for (int i = t; i < 4096; i += 256) {
            int cc = i >> 6, e = i & 63;
            Bs[e][cc] = nodes[((long)b * NKEY + m0 + cc) * EMB + e0 + e];
        }
        __syncthreads();
        for (int e = 0; e < 64; ++e) {
            float a0 = As[e][tr * 4 + 0], a1 = As[e][tr * 4 + 1];
            float a2 = As[e][tr * 4 + 2], a3 = As[e][tr * 4 + 3];
            float b0 = Bs[e][tc * 4 + 0], b1 = Bs[e][tc * 4 + 1];
            float b2 = Bs[e][tc * 4 + 2], b3 = Bs[e][tc * 4 + 3];
            acc[0][0] += a0 * b0; acc[0][1] += a0 * b1; acc[0][2] += a0 * b2; acc[0][3] += a0 * b3;
            acc[1][0] += a1 * b0; acc[1][1] += a1 * b1; acc[1][2] += a1 * b2; acc[1][3] += a1 * b3;
            acc[2][0] += a2 * b0; acc[2][1] += a2 * b1; acc[2][2] += a2 * b2; acc[2][3] += a2 * b3;
            acc[3][0] += a3 * b0; acc[3][1] += a3 * b1; acc[3][2] += a3 * b2; acc[3][3] += a3 * b3;
        }
        __syncthreads();
    }
    const float inv = 0.08838834764831845f;  // 1/sqrt(128)
    #pragma unroll
    for (int i = 0; i < 4; ++i) {
        int n = n0 + tr * 4 + i;
        if (n >= POMO) continue;
        #pragma unroll
        for (int j = 0; j < 4; ++j) {
            int m = m0 + tc * 4 + j;
            if (m >= NODE) continue;
            long idx = ((long)b * POMO + n) * NODE + m;
            out[idx] = tanh10(acc[i][j] * inv) + mask[idx];
        }
    }
}

// ---------------- in-place row softmax over 1000 (shfl reduce) --------------
__global__ __launch_bounds__(256) void softmax_kernel(float* __restrict__ out)
{
    __shared__ float wred[8];
    int t = threadIdx.x;
    int w = t >> 6;
    float* p = out + (long)blockIdx.x * NODE;
    bool act = t < 250;
    float4 x = act ? *(const float4*)&p[t * 4]
                   : make_float4(-1e30f, -1e30f, -1e30f, -1e30f);
    float mx = fmaxf(fmaxf(x.x, x.y), fmaxf(x.z, x.w));
    #pragma unroll
    for (int s = 32; s >= 1; s >>= 1) mx = fmaxf(mx, __shfl_xor(mx, s));
    if ((t & 63) == 0) wred[w] = mx;
    __syncthreads();
    float M = fmaxf(fmaxf(wred[0], wred[1]), fmaxf(wred[2], wred[3]));
    float4 e;
    e.x = __expf(x.x - M); e.y = __expf(x.y - M);
    e.z = __expf(x.z - M); e.w = __expf(x.w - M);
    float sm = e.x + e.y + e.z + e.w;
    #pragma unroll
    for (int s = 32; s >= 1; s >>= 1) sm += __shfl_xor(sm, s);
    if ((t & 63) == 0) wred[4 + w] = sm;
    __syncthreads();
    float inv = 1.0f / (wred[4] + wred[5] + wred[6] + wred[7]);
    if (act) {
        float4 rr;
        rr.x = e.x * inv; rr.y = e.y * inv; rr.z = e.z * inv; rr.w = e.w * inv;
        *(float4*)&p[t * 4] = rr;
    }
}

extern "C" void kernel_launch(void* const* d_in, const int* in_sizes, int n_in,
                              void* d_out, int out_size, void* d_ws, size_t ws_size,
                              hipStream_t stream)
{
    const float* pref  = (const float*)d_in[0];
    const float* nodes = (const float*)d_in[1];
    const float* q1    = (const float*)d_in[2];
    const float* lastn = (const float*)d_in[3];
    const float* mask  = (const float*)d_in[4];
    const float* fc1_w = (const float*)d_in[5];
    const float* fc1_b = (const float*)d_in[6];
    const float* fc2_w = (const float*)d_in[7];
    const float* fc2_b = (const float*)d_in[8];
    const float* fc3_w = (const float*)d_in[9];
    const float* fc3_b = (const float*)d_in[10];
    const float* wqf   = (const float*)d_in[11];
    const float* wql   = (const float*)d_in[12];
    const float* wk    = (const float*)d_in[13];
    const float* wv    = (const float*)d_in[14];
    const float* wc    = (const float*)d_in[15];
    float* out = (float*)d_out;
    float* ws  = (float*)d_ws;

    float* W5 = ws;                                   // 5*16384 = 81920
    float* Kb = ws + 81920;                           // 8*1196*128
    float* Vb = Kb + (long)BB * NKEY * EMB;
    float* Qb = Vb + (long)BB * NKEY * EMB;           // 8*1000*128
    float* OC = Qb + (long)BB * POMO * EMB;
    float* MH = OC + (long)BB * POMO * EMB;
    float* gmid = MH + (long)BB * POMO * EMB;         // 16 floats, ~22.4 MB total

    float* pacc = out;                 // d_out (32 MB) as partial scratch
    float* pl   = out + PACC_FLOATS;   // fully overwritten by logits later

    hipLaunchKernelGGL(hyper_mid_kernel, dim3(1), dim3(256), 0, stream,
                       pref, fc1_w, fc1_b, fc2_w, fc2_b, fc3_w, fc3_b, gmid);
    hipLaunchKernelGGL(hyper_expand_kernel, dim3(40), dim3(256), 0, stream,
                       gmid, wqf, wql, wk, wv, wc, W5);
    hipLaunchKernelGGL(kv_proj_kernel, dim3(299), dim3(256), 0, stream, nodes, W5, Kb, Vb);
    hipLaunchKernelGGL(q_proj_kernel, dim3(250), dim3(256), 0, stream, q1, lastn, W5, Qb);
    hipLaunchKernelGGL(attn_split_kernel, dim3(8, TILES16, SCH), dim3(128), 0, stream,
                       Kb, Vb, Qb, mask, pacc, pl);
    hipLaunchKernelGGL(attn_merge_kernel, dim3(8, TILES16), dim3(512), 0, stream, pacc, pl, OC);
    hipLaunchKernelGGL(combine_kernel, dim3(250), dim3(256), 0, stream, OC, W5, MH);
    hipLaunchKernelGGL(logits_kernel, dim3(8, 16, 16), dim3(256), 0, stream, MH, nodes, mask, out);
    hipLaunchKernelGGL(softmax_kernel, dim3(8000), dim3(256), 0, stream, out);
}

// Round 7
// 481.484 us; speedup vs baseline: 1.8802x; 1.8802x over previous
//
#include <hip/hip_runtime.h>
#include <math.h>

#define EMB 128
#define NH 8
#define DH 16
#define HID 256
#define NODE 1000
#define PATCH 196
#define NKEY (NODE + PATCH)   // 1196
#define BB 8
#define POMO 1000
#define KT 16                  // attention key tile
#define SCH 6                  // key-split chunks
#define CKEYS 200              // keys per chunk (last = 196)
#define TILES 42               // ceil(1000/24) row tiles
#define TROWS 24               // rows per tile (8 rr * 3)
#define RPT 3                  // rows per thread

// partial buffers alias d_out (8M floats):
// pacc: [b][tile42][chunk][row24][h][16] = 8*42*6*24*8*16 = 6,193,152 floats
// pl  : [b][tile42][chunk][h][row24]     = 8*42*6*8*24    =   387,072 floats
#define PACC_FLOATS 6193152L

__device__ __forceinline__ float tanh10(float x) {
    float e = __expf(2.0f * x);
    return 10.0f * (1.0f - 2.0f / (e + 1.0f));
}

// ---------------- hypernet stage 1: pref -> mid[15] -------------------------
__global__ __launch_bounds__(256) void hyper_mid_kernel(
    const float* __restrict__ pref,
    const float* __restrict__ fc1_w, const float* __restrict__ fc1_b,
    const float* __restrict__ fc2_w, const float* __restrict__ fc2_b,
    const float* __restrict__ fc3_w, const float* __restrict__ fc3_b,
    float* __restrict__ gmid)
{
    __shared__ float h1[HID];
    __shared__ float h2[HID];
    int t = threadIdx.x;
    float p0 = pref[0], p1 = pref[1], p2 = pref[2];
    h1[t] = fc1_b[t] + p0 * fc1_w[t * 3 + 0] + p1 * fc1_w[t * 3 + 1] + p2 * fc1_w[t * 3 + 2];
    __syncthreads();
    {
        float s = fc2_b[t];
        const float4* w4 = (const float4*)(fc2_w + t * HID);
        const float4* h4 = (const float4*)h1;
        for (int j = 0; j < HID / 4; ++j) {
            float4 w = w4[j], x = h4[j];
            s += x.x * w.x + x.y * w.y + x.z * w.z + x.w * w.w;
        }
        h2[t] = s;
    }
    __syncthreads();
    if (t < 15) {
        float s = fc3_b[t];
        const float4* w4 = (const float4*)(fc3_w + t * HID);
        const float4* h4 = (const float4*)h2;
        for (int j = 0; j < HID / 4; ++j) {
            float4 w = w4[j], x = h4[j];
            s += x.x * w.x + x.y * w.y + x.z * w.z + x.w * w.w;
        }
        gmid[t] = s;
    }
}

// ---------------- hypernet stage 2: mid -> 5 weight matrices ----------------
__global__ __launch_bounds__(256) void hyper_expand_kernel(
    const float* __restrict__ gmid,
    const float* __restrict__ wqf, const float* __restrict__ wql,
    const float* __restrict__ wk,  const float* __restrict__ wv,
    const float* __restrict__ wc,  float* __restrict__ W5)
{
    int id = blockIdx.x;                 // 40 blocks: 5 mats x 8 segments
    int mat = id >> 3;
    int x0 = (id & 7) * 2048 + threadIdx.x * 8;
    const float* w = (mat == 0) ? wqf : (mat == 1) ? wql : (mat == 2) ? wk : (mat == 3) ? wv : wc;
    float m0 = gmid[mat * 3 + 0], m1 = gmid[mat * 3 + 1], m2 = gmid[mat * 3 + 2];
    float* dst = W5 + mat * EMB * EMB;
    #pragma unroll
    for (int i = 0; i < 8; ++i) {
        int x = x0 + i;
        dst[x] = m0 * w[x * 3 + 0] + m1 * w[x * 3 + 1] + m2 * w[x * 3 + 2];
    }
}

// ---------------- K,V projection of encoded_nodes ---------------------------
__global__ __launch_bounds__(256) void kv_proj_kernel(
    const float* __restrict__ nodes, const float* __restrict__ W5,
    float* __restrict__ Kb, float* __restrict__ Vb)
{
    __shared__ float xs[32][EMB];
    int t = threadIdx.x;
    long r0 = (long)blockIdx.x * 32;            // over BB*NKEY = 9568 (299*32 exact)
    const float4* s4 = (const float4*)(nodes + r0 * EMB);
    float4* x4p = (float4*)&xs[0][0];
    for (int i = t; i < 32 * EMB / 4; i += 256) x4p[i] = s4[i];
    __syncthreads();
    int o = t;
    const float* W = (o < EMB) ? (W5 + 2 * EMB * EMB + o * EMB)
                               : (W5 + 3 * EMB * EMB + (o - EMB) * EMB);
    float acc[32];
    #pragma unroll
    for (int r = 0; r < 32; ++r) acc[r] = 0.f;
    for (int e = 0; e < EMB; e += 4) {
        float4 w4 = *(const float4*)&W[e];
        #pragma unroll
        for (int r = 0; r < 32; ++r) {
            float4 x4 = *(const float4*)&xs[r][e];
            acc[r] += x4.x * w4.x + x4.y * w4.y + x4.z * w4.z + x4.w * w4.w;
        }
    }
    float* dst = (o < EMB) ? (Kb + r0 * EMB + o) : (Vb + r0 * EMB + (o - EMB));
    #pragma unroll
    for (int r = 0; r < 32; ++r) dst[(long)r * EMB] = acc[r];
}

// ---------------- Q projection: q1@Wqf.T + last@Wql.T -----------------------
__global__ __launch_bounds__(256) void q_proj_kernel(
    const float* __restrict__ q1, const float* __restrict__ lastn,
    const float* __restrict__ W5, float* __restrict__ Qb)
{
    __shared__ float xa[32][EMB];
    __shared__ float xb[32][EMB];
    int t = threadIdx.x;
    long r0 = (long)blockIdx.x * 32;            // over 8000 (250*32 exact)
    const float4* a4 = (const float4*)(q1 + r0 * EMB);
    const float4* b4 = (const float4*)(lastn + r0 * EMB);
    float4* xap = (float4*)&xa[0][0];
    float4* xbp = (float4*)&xb[0][0];
    for (int i = t; i < 32 * EMB / 4; i += 256) { xap[i] = a4[i]; xbp[i] = b4[i]; }
    __syncthreads();
    int o = t & 127;
    int rbase = (t >> 7) * 16;
    const float* Wf = W5 + 0 * EMB * EMB + o * EMB;
    const float* Wl = W5 + 1 * EMB * EMB + o * EMB;
    float acc[16];
    #pragma unroll
    for (int r = 0; r < 16; ++r) acc[r] = 0.f;
    for (int e = 0; e < EMB; e += 4) {
        float4 wf = *(const float4*)&Wf[e];
        float4 wl = *(const float4*)&Wl[e];
        #pragma unroll
        for (int r = 0; r < 16; ++r) {
            float4 va = *(const float4*)&xa[rbase + r][e];
            float4 vb = *(const float4*)&xb[rbase + r][e];
            acc[r] += va.x * wf.x + va.y * wf.y + va.z * wf.z + va.w * wf.w
                    + vb.x * wl.x + vb.y * wl.y + vb.z * wl.z + vb.w * wl.w;
        }
    }
    #pragma unroll
    for (int r = 0; r < 16; ++r) Qb[(r0 + rbase + r) * EMB + o] = acc[r];
}

// ---------------- fused masked MHA, key-split, no-max-shift -----------------
// SINGLE-WAVE blocks: 64 threads = 8h x 8rr, RPT=3 rows/thread, NO barriers
// (wave stages its own K/V tile; ordering via lgkmcnt-only wait -> global
// prefetches never drained by s_barrier). LDS padded [16][8][20]: the 8
// h-group broadcast addresses land on 8 disjoint bank quads -> conflict-free.
// grid (8, 42, 6): x=b (XCD-aligned), y=24-row tile, z=key chunk.
__global__ __launch_bounds__(64, 1) void attn_split_kernel(
    const float* __restrict__ Kb, const float* __restrict__ Vb,
    const float* __restrict__ Qb, const float* __restrict__ mask,
    float* __restrict__ pacc, float* __restrict__ pl)
{
    __shared__ float ks[KT][NH][20];
    __shared__ float vs[KT][NH][20];
    int t = threadIdx.x;
    int b = blockIdx.x, tile = blockIdx.y, c = blockIdx.z;
    int rr = t & 7, h = t >> 3;
    int row0 = tile * TROWS + rr * RPT;
    int kstart = c * CKEYS;
    int kend = kstart + CKEYS; if (kend > NKEY) kend = NKEY;
    bool has_mask = (kstart < NODE);   // chunks 0..4 node keys, 5 pure patch

    int qrow[RPT];
    float q[RPT][DH], acc[RPT][DH], l[RPT];
    #pragma unroll
    for (int r = 0; r < RPT; ++r) {
        int rw = row0 + r;
        qrow[r] = (rw < POMO) ? rw : (POMO - 1);   // clamp; stores guarded
        const float4* qp = (const float4*)(Qb + ((long)b * POMO + qrow[r]) * EMB + h * DH);
        #pragma unroll
        for (int i = 0; i < 4; ++i) {
            float4 v = qp[i];   // pre-scale by 1/sqrt(16): s = q.k + mask
            q[r][4*i+0] = v.x*0.25f; q[r][4*i+1] = v.y*0.25f;
            q[r][4*i+2] = v.z*0.25f; q[r][4*i+3] = v.w*0.25f;
        }
        #pragma unroll
        for (int i = 0; i < DH; ++i) acc[r][i] = 0.f;
        l[r] = 0.f;
    }

    const float4* ksrc = (const float4*)(Kb + (long)b * NKEY * EMB);
    const float4* vsrc = (const float4*)(Vb + (long)b * NKEY * EMB);
    const int max4 = NKEY * (EMB / 4) - 1;
    const float4 z4 = make_float4(0.f, 0.f, 0.f, 0.f);

    for (int t0 = kstart; t0 < kend; t0 += KT) {
        int valid = kend - t0; if (valid > KT) valid = KT;   // 16, 8 or 4
        int base4 = t0 * (EMB / 4);

        // two-pass staging (caps transient regs at 32); sched_barrier keeps
        // the passes from fusing into one 64-reg window.
#define STAGE_PASS(U0)                                                       \
        {                                                                    \
            float4 kr[4], vr[4];                                             \
            _Pragma("unroll")                                                \
            for (int u = 0; u < 4; ++u) {                                    \
                int li = t + (U0 + u) * 64;                                  \
                int src = base4 + li; if (src > max4) src = max4;            \
                kr[u] = ksrc[src]; vr[u] = vsrc[src];                        \
            }                                                                \
            _Pragma("unroll")                                                \
            for (int u = 0; u < 4; ++u) {                                    \
                int li = t + (U0 + u) * 64;                                  \
                int j = li >> 5, f = li & 31;                                \
                *(float4*)&ks[j][f >> 2][(f & 3) * 4] = kr[u];               \
                *(float4*)&vs[j][f >> 2][(f & 3) * 4] = vr[u];               \
            }                                                                \
        }
        STAGE_PASS(0)
        __builtin_amdgcn_sched_barrier(0);
        STAGE_PASS(4)
#undef STAGE_PASS
        asm volatile("s_waitcnt lgkmcnt(0)" ::: "memory");
        __builtin_amdgcn_sched_barrier(0);

        int mv4 = valid >> 2;

#define TILE_COMPUTE(TAIL)                                                    \
        _Pragma("unroll")                                                     \
        for (int j4 = 0; j4 < KT / 4; ++j4) {                                 \
            float4 m4[RPT];                                                   \
            if (has_mask) {                                                   \
                _Pragma("unroll")                                             \
                for (int r = 0; r < RPT; ++r) {                               \
                    const float4* mp = (const float4*)(mask +                 \
                        ((long)b * POMO + qrow[r]) * NODE + t0);              \
                    m4[r] = (!TAIL || j4 < mv4) ? mp[j4] : z4;                \
                }                                                             \
            } else {                                                          \
                _Pragma("unroll")                                             \
                for (int r = 0; r < RPT; ++r) m4[r] = z4;                     \
            }                                                                 \
            _Pragma("unroll")                                                 \
            for (int jj = 0; jj < 4; ++jj) {                                  \
                int j = j4 * 4 + jj;                                          \
                float4 k0 = *(const float4*)&ks[j][h][0];                     \
                float4 k1 = *(const float4*)&ks[j][h][4];                     \
                float4 k2 = *(const float4*)&ks[j][h][8];                     \
                float4 k3 = *(const float4*)&ks[j][h][12];                    \
                float p[RPT];                                                 \
                _Pragma("unroll")                                             \
                for (int r = 0; r < RPT; ++r) {                               \
                    float s = (jj == 0) ? m4[r].x : (jj == 1) ? m4[r].y       \
                            : (jj == 2) ? m4[r].z : m4[r].w;                  \
                    s += q[r][0]*k0.x + q[r][1]*k0.y + q[r][2]*k0.z + q[r][3]*k0.w; \
                    s += q[r][4]*k1.x + q[r][5]*k1.y + q[r][6]*k1.z + q[r][7]*k1.w; \
                    s += q[r][8]*k2.x + q[r][9]*k2.y + q[r][10]*k2.z + q[r][11]*k2.w; \
                    s += q[r][12]*k3.x + q[r][13]*k3.y + q[r][14]*k3.z + q[r][15]*k3.w; \
                    float pv = __expf(s);                                     \
                    if (TAIL && j >= valid) pv = 0.f;                         \
                    p[r] = pv; l[r] += pv;                                    \
                }                                                             \
                float4 v0 = *(const float4*)&vs[j][h][0];                     \
                float4 v1 = *(const float4*)&vs[j][h][4];                     \
                float4 v2 = *(const float4*)&vs[j][h][8];                     \
                float4 v3 = *(const float4*)&vs[j][h][12];                    \
                _Pragma("unroll")                                             \
                for (int r = 0; r < RPT; ++r) {                               \
                    acc[r][0] += p[r]*v0.x;  acc[r][1] += p[r]*v0.y;          \
                    acc[r][2] += p[r]*v0.z;  acc[r][3] += p[r]*v0.w;          \
                    acc[r][4] += p[r]*v1.x;  acc[r][5] += p[r]*v1.y;          \
                    acc[r][6] += p[r]*v1.z;  acc[r][7] += p[r]*v1.w;          \
                    acc[r][8] += p[r]*v2.x;  acc[r][9] += p[r]*v2.y;          \
                    acc[r][10] += p[r]*v2.z; acc[r][11] += p[r]*v2.w;         \
                    acc[r][12] += p[r]*v3.x; acc[r][13] += p[r]*v3.y;         \
                    acc[r][14] += p[r]*v3.z; acc[r][15] += p[r]*v3.w;         \
                }                                                             \
            }                                                                 \
        }
        if (valid == KT) { TILE_COMPUTE(false) } else { TILE_COMPUTE(true) }
#undef TILE_COMPUTE
        // next iteration overwrites ks/vs; per-wave DS ops complete in order,
        // and the "memory" asm at the top of the next tile blocks reordering.
    }

    long cb = ((long)(b * TILES + tile) * SCH + c);
    #pragma unroll
    for (int r = 0; r < RPT; ++r) {
        if (row0 + r < POMO) {
            long rec = ((cb * TROWS + rr * RPT + r) * NH + h) * 16;
            #pragma unroll
            for (int i = 0; i < 4; ++i)
                *(float4*)&pacc[rec + 4*i] =
                    make_float4(acc[r][4*i], acc[r][4*i+1], acc[r][4*i+2], acc[r][4*i+3]);
            pl[(cb * NH + h) * TROWS + rr * RPT + r] = l[r];
        }
    }
}

// ---------------- merge key-split partials -> OC (plain sums) ---------------
__global__ __launch_bounds__(192) void attn_merge_kernel(
    const float* __restrict__ pacc, const float* __restrict__ pl,
    float* __restrict__ OC)
{
    int t = threadIdx.x;          // t = rt*8 + h, 192 threads
    int b = blockIdx.x, tile = blockIdx.y;
    int rt = t >> 3, h = t & 7;
    int row = tile * TROWS + rt;
    if (row >= POMO) return;
    long cb0 = (long)(b * TILES + tile) * SCH;
    const long cs_acc = (long)TROWS * NH * 16;   // 3072 floats per chunk
    long abase = cb0 * cs_acc + ((long)rt * NH + h) * 16;
    const long cs_pl = (long)NH * TROWS;         // 192 floats per chunk
    long lbase = cb0 * cs_pl + (long)h * TROWS + rt;

    float L = 0.f;
    float o[16];
    #pragma unroll
    for (int i = 0; i < 16; ++i) o[i] = 0.f;
    #pragma unroll
    for (int c = 0; c < SCH; ++c) {
        L += pl[lbase + c * cs_pl];
        #pragma unroll
        for (int i4 = 0; i4 < 4; ++i4) {
            float4 a = *(const float4*)&pacc[abase + c * cs_acc + 4 * i4];
            o[4*i4+0] += a.x; o[4*i4+1] += a.y;
            o[4*i4+2] += a.z; o[4*i4+3] += a.w;
        }
    }
    float inv = 1.0f / L;
    float* op = OC + ((long)b * POMO + row) * EMB + h * DH;
    #pragma unroll
    for (int i4 = 0; i4 < 4; ++i4)
        *(float4*)&op[4*i4] = make_float4(o[4*i4]*inv, o[4*i4+1]*inv,
                                          o[4*i4+2]*inv, o[4*i4+3]*inv);
}

// ---------------- multi-head combine: mh = oc @ Wc.T ------------------------
__global__ __launch_bounds__(256) void combine_kernel(
    const float* __restrict__ OC, const float* __restrict__ W5,
    float* __restrict__ MH)
{
    __shared__ float xs[32][EMB];
    int t = threadIdx.x;
    long r0 = (long)blockIdx.x * 32;            // over 8000
    const float4* s4 = (const float4*)(OC + r0 * EMB);
    float4* xp = (float4*)&xs[0][0];
    for (int i = t; i < 32 * EMB / 4; i += 256) xp[i] = s4[i];
    __syncthreads();
    int o = t & 127;
    int rbase = (t >> 7) * 16;
    const float* W = W5 + 4 * EMB * EMB + o * EMB;
    float acc[16];
    #pragma unroll
    for (int r = 0; r < 16; ++r) acc[r] = 0.f;
    for (int e = 0; e < EMB; e += 4) {
        float4 w4 = *(const float4*)&W[e];
        #pragma unroll
        for (int r = 0; r < 16; ++r) {
            float4 x4 = *(const float4*)&xs[rbase + r][e];
            acc[r] += x4.x * w4.x + x4.y * w4.y + x4.z * w4.z + x4.w * w4.w;
        }
    }
    #pragma unroll
    for (int r = 0; r < 16; ++r) MH[(r0 + rbase + r) * EMB + o] = acc[r];
}

// ---------------- logits: 10*tanh((mh @ nodes.T)/sqrt(128)) + mask ----------
__global__ __launch_bounds__(256) void logits_kernel(
    const float* __restrict__ MH, const float* __restrict__ nodes,
    const float* __restrict__ mask, float* __restrict__ out)
{
    __shared__ float As[64][65];   // [e][r]
    __shared__ float Bs[64][65];   // [e][c]
    int t = threadIdx.x;
    int b = blockIdx.x;
    int m0 = blockIdx.y * 64;
    int n0 = blockIdx.z * 64;
    int tc = t & 15, tr = t >> 4;
    float acc[4][4];
    #pragma unroll
    for (int i = 0; i < 4; ++i)
        #pragma unroll
        for (int j = 0; j < 4; ++j) acc[i][j] = 0.f;

    for (int e0 = 0; e0 < EMB; e0 += 64) {
        for (int i = t; i < 4096; i += 256) {
            int rr = i >> 6, e = i & 63;
            int n = n0 + rr;
            As[e][rr] = (n < POMO) ? MH[((long)b * POMO + n) * EMB + e0 + e] : 0.f;
        }
        for (int i = t; i < 4096; i += 256) {
            int cc = i >> 6, e = i & 63;
            Bs[e][cc] = nodes[((long)b * NKEY + m0 + cc) * EMB + e0 + e];
        }
        __syncthreads();
        for (int e = 0; e < 64; ++e) {
            float a0 = As[e][tr * 4 + 0], a1 = As[e][tr * 4 + 1];
            float a2 = As[e][tr * 4 + 2], a3 = As[e][tr * 4 + 3];
            float b0 = Bs[e][tc * 4 + 0], b1 = Bs[e][tc * 4 + 1];
            float b2 = Bs[e][tc * 4 + 2], b3 = Bs[e][tc * 4 + 3];
            acc[0][0] += a0 * b0; acc[0][1] += a0 * b1; acc[0][2] += a0 * b2; acc[0][3] += a0 * b3;
            acc[1][0] += a1 * b0; acc[1][1] += a1 * b1; acc[1][2] += a1 * b2; acc[1][3] += a1 * b3;
            acc[2][0] += a2 * b0; acc[2][1] += a2 * b1; acc[2][2] += a2 * b2; acc[2][3] += a2 * b3;
            acc[3][0] += a3 * b0; acc[3][1] += a3 * b1; acc[3][2] += a3 * b2; acc[3][3] += a3 * b3;
        }
        __syncthreads();
    }
    const float inv = 0.08838834764831845f;  // 1/sqrt(128)
    #pragma unroll
    for (int i = 0; i < 4; ++i) {
        int n = n0 + tr * 4 + i;
        if (n >= POMO) continue;
        #pragma unroll
        for (int j = 0; j < 4; ++j) {
            int m = m0 + tc * 4 + j;
            if (m >= NODE) continue;
            long idx = ((long)b * POMO + n) * NODE + m;
            out[idx] = tanh10(acc[i][j] * inv) + mask[idx];
        }
    }
}

// ---------------- in-place row softmax over 1000 (shfl reduce) --------------
__global__ __launch_bounds__(256) void softmax_kernel(float* __restrict__ out)
{
    __shared__ float wred[8];
    int t = threadIdx.x;
    int w = t >> 6;
    float* p = out + (long)blockIdx.x * NODE;
    bool act = t < 250;
    float4 x = act ? *(const float4*)&p[t * 4]
                   : make_float4(-1e30f, -1e30f, -1e30f, -1e30f);
    float mx = fmaxf(fmaxf(x.x, x.y), fmaxf(x.z, x.w));
    #pragma unroll
    for (int s = 32; s >= 1; s >>= 1) mx = fmaxf(mx, __shfl_xor(mx, s));
    if ((t & 63) == 0) wred[w] = mx;
    __syncthreads();
    float M = fmaxf(fmaxf(wred[0], wred[1]), fmaxf(wred[2], wred[3]));
    float4 e;
    e.x = __expf(x.x - M); e.y = __expf(x.y - M);
    e.z = __expf(x.z - M); e.w = __expf(x.w - M);
    float sm = e.x + e.y + e.z + e.w;
    #pragma unroll
    for (int s = 32; s >= 1; s >>= 1) sm += __shfl_xor(sm, s);
    if ((t & 63) == 0) wred[4 + w] = sm;
    __syncthreads();
    float inv = 1.0f / (wred[4] + wred[5] + wred[6] + wred[7]);
    if (act) {
        float4 rr;
        rr.x = e.x * inv; rr.y = e.y * inv; rr.z = e.z * inv; rr.w = e.w * inv;
        *(float4*)&p[t * 4] = rr;
    }
}

extern "C" void kernel_launch(void* const* d_in, const int* in_sizes, int n_in,
                              void* d_out, int out_size, void* d_ws, size_t ws_size,
                              hipStream_t stream)
{
    const float* pref  = (const float*)d_in[0];
    const float* nodes = (const float*)d_in[1];
    const float* q1    = (const float*)d_in[2];
    const float* lastn = (const float*)d_in[3];
    const float* mask  = (const float*)d_in[4];
    const float* fc1_w = (const float*)d_in[5];
    const float* fc1_b = (const float*)d_in[6];
    const float* fc2_w = (const float*)d_in[7];
    const float* fc2_b = (const float*)d_in[8];
    const float* fc3_w = (const float*)d_in[9];
    const float* fc3_b = (const float*)d_in[10];
    const float* wqf   = (const float*)d_in[11];
    const float* wql   = (const float*)d_in[12];
    const float* wk    = (const float*)d_in[13];
    const float* wv    = (const float*)d_in[14];
    const float* wc    = (const float*)d_in[15];
    float* out = (float*)d_out;
    float* ws  = (float*)d_ws;

    float* W5 = ws;                                   // 5*16384 = 81920
    float* Kb = ws + 81920;                           // 8*1196*128
    float* Vb = Kb + (long)BB * NKEY * EMB;
    float* Qb = Vb + (long)BB * NKEY * EMB;           // 8*1000*128
    float* OC = Qb + (long)BB * POMO * EMB;
    float* MH = OC + (long)BB * POMO * EMB;
    float* gmid = MH + (long)BB * POMO * EMB;         // 16 floats, ~22.4 MB total

    float* pacc = out;                 // d_out (32 MB) as partial scratch
    float* pl   = out + PACC_FLOATS;   // fully overwritten by logits later

    hipLaunchKernelGGL(hyper_mid_kernel, dim3(1), dim3(256), 0, stream,
                       pref, fc1_w, fc1_b, fc2_w, fc2_b, fc3_w, fc3_b, gmid);
    hipLaunchKernelGGL(hyper_expand_kernel, dim3(40), dim3(256), 0, stream,
                       gmid, wqf, wql, wk, wv, wc, W5);
    hipLaunchKernelGGL(kv_proj_kernel, dim3(299), dim3(256), 0, stream, nodes, W5, Kb, Vb);
    hipLaunchKernelGGL(q_proj_kernel, dim3(250), dim3(256), 0, stream, q1, lastn, W5, Qb);
    hipLaunchKernelGGL(attn_split_kernel, dim3(8, TILES, SCH), dim3(64), 0, stream,
                       Kb, Vb, Qb, mask, pacc, pl);
    hipLaunchKernelGGL(attn_merge_kernel, dim3(8, TILES), dim3(192), 0, stream, pacc, pl, OC);
    hipLaunchKernelGGL(combine_kernel, dim3(250), dim3(256), 0, stream, OC, W5, MH);
    hipLaunchKernelGGL(logits_kernel, dim3(8, 16, 16), dim3(256), 0, stream, MH, nodes, mask, out);
    hipLaunchKernelGGL(softmax_kernel, dim3(8000), dim3(256), 0, stream, out);
}